// Round 1
// baseline (741.081 us; speedup 1.0000x reference)
//
#include <hip/hip_runtime.h>

// Sobel3D fused (fp32): gx, gy, gz (depthwise separable 3x3x3) in one pass.
//
// R1: software-pipelined plane prefetch + nontemporal stores.
// R0 post-mortem: top-5 rocprof dispatches are all 2.4 GB harness poison fills
// at ~385 us (6.3 TB/s = achievable ceiling); the sobel dispatch is < 380 us,
// so dur_us=729 ~= fill(385) + kernel(~344). Kernel at ~344 us moves ~805 MB
// -> 2.3 TB/s effective: latency-bound (in-iteration load->use vmcnt wait at
// ~4 waves/SIMD occupancy), not BW-bound. Fix: hold plane z+1 raw rows in
// registers, issue plane z+2 loads BEFORE computing z+1 combos (load issue and
// use a full iteration apart); nontemporal stores keep the write-once output
// from thrashing L3 so the 201 MB input stays L3-resident; pow-2 incremental
// addressing kills the per-iter 64-bit mul chains.
//
// Decomposition (XLA conv = cross-correlation, no kernel flip):
//   per plane z: A = S_h*D_w, B = D_h*S_w, C = S_h*S_w   (2D combos)
//   gx[d] = A(d-1) + 2A(d) + A(d+1)
//   gy[d] = B(d-1) + 2B(d) + B(d+1)
//   gz[d] = C(d+1) - C(d-1)
// Thread: 4 consecutive w (float4, 16B I/O), rolls along d. w-halo via wave
// shuffles (edge lanes are the zero-pad boundary), h-halo via direct loads
// (cache-served), d-halo via rolling registers.

#define DDIM 96
#define HDIM 128
#define WDIM 128
#define NCIMG 32                                  // N*C = 2*16
#define NTOT ((size_t)NCIMG * DDIM * HDIM * WDIM) // 50331648 per output tensor
#define DCHUNK 24
#define PLANE (HDIM * WDIM)                       // 16384 = 1<<14

typedef float f4 __attribute__((ext_vector_type(4)));

__global__ __launch_bounds__(256, 2)
void sobel3d_fused(const float* __restrict__ x, float* __restrict__ out) {
  const int wx = threadIdx.x;            // 0..31 (w-chunk within row)
  const int w0 = wx << 2;                // 0,4,...,124
  const int h  = blockIdx.y * 8 + threadIdx.y;
  const int nc = blockIdx.z >> 2;        // image index 0..31
  const int d0 = (blockIdx.z & 3) * DCHUNK;

  const float* img = x + (size_t)nc * (DDIM * PLANE);

  // h-halo: clamped row indices + zero-pad scale (uniform per thread; lanes
  // shuffled with are the same row, so scaling before shuffle is safe).
  const int   hm = (h > 0) ? h - 1 : 0;
  const int   hp = (h < HDIM - 1) ? h + 1 : h;
  const float sm = (h > 0) ? 1.f : 0.f;
  const float sp = (h < HDIM - 1) ? 1.f : 0.f;

  // Issue the 3 row loads of plane z (pure issue; no wait until use).
  auto loadPlane = [&](int z, f4& vm, f4& v0, f4& vp) {
    const float* p = img + ((size_t)z << 14) + w0;
    vm = *(const f4*)(p + (hm << 7));
    v0 = *(const f4*)(p + (h  << 7));
    vp = *(const f4*)(p + (hp << 7));
  };

  // Row smooth (P = S_w) and derivative (Q = D_w) with w-halo via shuffles.
  auto rowPQ = [&](f4 v, float s, float* P, float* Q) {
    const float x0 = v.x * s, x1 = v.y * s, x2 = v.z * s, x3 = v.w * s;
    float xm = __shfl_up(x3, 1);         // left neighbor's elem 3  (w0-1)
    float xp = __shfl_down(x0, 1);       // right neighbor's elem 0 (w0+4)
    if (wx == 0)  xm = 0.f;              // w = -1  -> zero pad
    if (wx == 31) xp = 0.f;              // w = 128 -> zero pad
    P[0] = xm + 2.f * x0 + x1;  Q[0] = x1 - xm;
    P[1] = x0 + 2.f * x1 + x2;  Q[1] = x2 - x0;
    P[2] = x1 + 2.f * x2 + x3;  Q[2] = x3 - x1;
    P[3] = x2 + 2.f * x3 + xp;  Q[3] = xp - x2;
  };

  // 2D combos of one plane from its 3 raw rows (already in registers).
  auto combos = [&](f4 vm, f4 v0, f4 vp, float* A, float* B, float* C) {
    float Pm[4], Qm[4], P0[4], Q0[4], Pp[4], Qp[4];
    rowPQ(vm, sm, Pm, Qm);
    rowPQ(v0, 1.f, P0, Q0);
    rowPQ(vp, sp, Pp, Qp);
#pragma unroll
    for (int j = 0; j < 4; ++j) {
      A[j] = Qm[j] + 2.f * Q0[j] + Qp[j];   // S_h * D_w
      B[j] = Pp[j] - Pm[j];                 // D_h * S_w
      C[j] = Pm[j] + 2.f * P0[j] + Pp[j];   // S_h * S_w
    }
  };

  float A0[4], B0[4], C0[4], A1[4], B1[4], C1[4];
  f4 rm, r0, rp;                         // raw rows of plane d+1 (pipelined)

  // Prime: combos for planes d0-1 (zero if OOB) and d0; raw rows for d0+1.
  {
    const int zm = d0 - 1;
    f4 a, b, c;
    loadPlane(zm < 0 ? 0 : zm, a, b, c);
    combos(a, b, c, A0, B0, C0);
    if (zm < 0) {
#pragma unroll
      for (int j = 0; j < 4; ++j) { A0[j] = 0.f; B0[j] = 0.f; C0[j] = 0.f; }
    }
  }
  {
    f4 a, b, c;
    loadPlane(d0, a, b, c);
    combos(a, b, c, A1, B1, C1);
  }
  loadPlane(d0 + 1, rm, r0, rp);         // d0+1 <= 73 < 96: always in range

  size_t o = (((size_t)nc * DDIM + d0) * HDIM + h) * WDIM + w0;

#pragma unroll 2
  for (int d = d0; d < d0 + DCHUNK; ++d) {
    // 1) ISSUE loads for plane d+2 (consumed next iteration).
    f4 nm, n0, np;
    const int zn = d + 2;
    loadPlane(zn >= DDIM ? DDIM - 1 : zn, nm, n0, np);

    // 2) Compute combos for plane d+1 from registers loaded last iteration.
    float A2[4], B2[4], C2[4];
    combos(rm, r0, rp, A2, B2, C2);
    if (d + 1 >= DDIM) {                 // only last iter of last chunk
#pragma unroll
      for (int j = 0; j < 4; ++j) { A2[j] = 0.f; B2[j] = 0.f; C2[j] = 0.f; }
    }

    // 3) Combine along d and store (nontemporal: write-once, never re-read).
    f4 gx, gy, gz;
    gx.x = A0[0] + 2.f * A1[0] + A2[0];
    gx.y = A0[1] + 2.f * A1[1] + A2[1];
    gx.z = A0[2] + 2.f * A1[2] + A2[2];
    gx.w = A0[3] + 2.f * A1[3] + A2[3];
    gy.x = B0[0] + 2.f * B1[0] + B2[0];
    gy.y = B0[1] + 2.f * B1[1] + B2[1];
    gy.z = B0[2] + 2.f * B1[2] + B2[2];
    gy.w = B0[3] + 2.f * B1[3] + B2[3];
    gz.x = C2[0] - C0[0];
    gz.y = C2[1] - C0[1];
    gz.z = C2[2] - C0[2];
    gz.w = C2[3] - C0[3];
    __builtin_nontemporal_store(gx, (f4*)(out + o));
    __builtin_nontemporal_store(gy, (f4*)(out + NTOT + o));
    __builtin_nontemporal_store(gz, (f4*)(out + 2 * NTOT + o));
    o += PLANE;

    // 4) Roll state (renamed away by unroll).
#pragma unroll
    for (int j = 0; j < 4; ++j) {
      A0[j] = A1[j]; B0[j] = B1[j]; C0[j] = C1[j];
      A1[j] = A2[j]; B1[j] = B2[j]; C1[j] = C2[j];
    }
    rm = nm; r0 = n0; rp = np;
  }
}

extern "C" void kernel_launch(void* const* d_in, const int* in_sizes, int n_in,
                              void* d_out, int out_size, void* d_ws, size_t ws_size,
                              hipStream_t stream) {
  const float* x = (const float*)d_in[0];
  float* out = (float*)d_out;
  dim3 block(32, 8, 1);
  dim3 grid(1, HDIM / 8, NCIMG * (DDIM / DCHUNK));  // (1, 16, 128)
  hipLaunchKernelGGL(sobel3d_fused, grid, block, 0, stream, x, out);
}

// Round 2
// 737.315 us; speedup vs baseline: 1.0051x; 1.0051x over previous
//
#include <hip/hip_runtime.h>

// Sobel3D fused (fp32): gx, gy, gz (depthwise separable 3x3x3) in one pass.
//
// R2: occupancy 2 -> 4 blocks/CU (__launch_bounds__(256,4)) + 32-bit offset
// addressing to fit the 128-VGPR cap.
// R1 post-mortem: software pipelining + NT stores were NEUTRAL (729.7->741.1,
// noise). The sobel dispatch is invisible to rocprof (graph-embedded); timed
// region ~= 2.4 GB poison fill (~386 us) + kernel (~355 us = 2.3 TB/s for
// ~805 MB traffic). The fill hits 6.27 TB/s in the same capture with deep
// per-wave store queues; our kernel at 2 waves/SIMD x ~6 VMEM in flight is
// MLP-capped (Little's law: ~12-48 KB/CU in flight -> 2-4 TB/s). Lever:
// double resident waves, not per-wave pipelining.
//
// Decomposition (XLA conv = cross-correlation, no kernel flip):
//   per plane z: A = S_h*D_w, B = D_h*S_w, C = S_h*S_w   (2D combos)
//   gx[d] = A(d-1) + 2A(d) + A(d+1)
//   gy[d] = B(d-1) + 2B(d) + B(d+1)
//   gz[d] = C(d+1) - C(d-1)
// Thread: 4 consecutive w (float4, 16B I/O), rolls along d. w-halo via wave
// shuffles (edge lanes are the zero-pad boundary), h-halo via direct loads
// (cache-served), d-halo via rolling registers.

#define DDIM 96
#define HDIM 128
#define WDIM 128
#define NCIMG 32                                   // N*C = 2*16
#define NTOTI 50331648                             // elements per output tensor (int)
#define DCHUNK 24
#define PLANE (HDIM * WDIM)                        // 16384 = 1<<14

typedef float f4 __attribute__((ext_vector_type(4)));

__global__ __launch_bounds__(256, 4)
void sobel3d_fused(const float* __restrict__ x, float* __restrict__ out) {
  const int wx = threadIdx.x;            // 0..31 (w-chunk within row)
  const int w0 = wx << 2;                // 0,4,...,124
  const int h  = blockIdx.y * 8 + threadIdx.y;
  const int nc = blockIdx.z >> 2;        // image index 0..31
  const int d0 = (blockIdx.z & 3) * DCHUNK;

  // Uniform SGPR base for this image; all further offsets are 32-bit ints
  // (input image = 6.3 MB, fits easily) -> saddr-form loads, fewer VGPRs.
  const float* img = x + (size_t)nc * (DDIM * PLANE);

  // h-halo: clamped row offsets + zero-pad scale (uniform per thread; lanes
  // shuffled with are the same row, so scaling before shuffle is safe).
  const int   om = (h > 0) ? ((h - 1) << 7) + w0 : w0;
  const int   o0 = (h << 7) + w0;
  const int   op = ((h < HDIM - 1) ? ((h + 1) << 7) : (h << 7)) + w0;
  const float sm = (h > 0) ? 1.f : 0.f;
  const float sp = (h < HDIM - 1) ? 1.f : 0.f;

  // Issue the 3 row loads of plane z (pure issue; no wait until use).
  auto loadPlane = [&](int z, f4& vm, f4& v0, f4& vp) {
    const int zb = z << 14;
    vm = *(const f4*)(img + zb + om);
    v0 = *(const f4*)(img + zb + o0);
    vp = *(const f4*)(img + zb + op);
  };

  // Row smooth (P = S_w) and derivative (Q = D_w) with w-halo via shuffles.
  auto rowPQ = [&](f4 v, float s, float* P, float* Q) {
    const float x0 = v.x * s, x1 = v.y * s, x2 = v.z * s, x3 = v.w * s;
    float xm = __shfl_up(x3, 1);         // left neighbor's elem 3  (w0-1)
    float xp = __shfl_down(x0, 1);       // right neighbor's elem 0 (w0+4)
    if (wx == 0)  xm = 0.f;              // w = -1  -> zero pad
    if (wx == 31) xp = 0.f;              // w = 128 -> zero pad
    P[0] = xm + 2.f * x0 + x1;  Q[0] = x1 - xm;
    P[1] = x0 + 2.f * x1 + x2;  Q[1] = x2 - x0;
    P[2] = x1 + 2.f * x2 + x3;  Q[2] = x3 - x1;
    P[3] = x2 + 2.f * x3 + xp;  Q[3] = xp - x2;
  };

  // 2D combos of one plane from its 3 raw rows (already in registers).
  auto combos = [&](f4 vm, f4 v0, f4 vp, float* A, float* B, float* C) {
    float Pm[4], Qm[4], P0[4], Q0[4], Pp[4], Qp[4];
    rowPQ(vm, sm, Pm, Qm);
    rowPQ(v0, 1.f, P0, Q0);
    rowPQ(vp, sp, Pp, Qp);
#pragma unroll
    for (int j = 0; j < 4; ++j) {
      A[j] = Qm[j] + 2.f * Q0[j] + Qp[j];   // S_h * D_w
      B[j] = Pp[j] - Pm[j];                 // D_h * S_w
      C[j] = Pm[j] + 2.f * P0[j] + Pp[j];   // S_h * S_w
    }
  };

  float A0[4], B0[4], C0[4], A1[4], B1[4], C1[4];
  f4 rm, r0, rp;                         // raw rows of plane d+1 (pipelined)

  // Prime: combos for planes d0-1 (zero if OOB) and d0; raw rows for d0+1.
  {
    const int zm = d0 - 1;
    f4 a, b, c;
    loadPlane(zm < 0 ? 0 : zm, a, b, c);
    combos(a, b, c, A0, B0, C0);
    if (zm < 0) {
#pragma unroll
      for (int j = 0; j < 4; ++j) { A0[j] = 0.f; B0[j] = 0.f; C0[j] = 0.f; }
    }
  }
  {
    f4 a, b, c;
    loadPlane(d0, a, b, c);
    combos(a, b, c, A1, B1, C1);
  }
  loadPlane(d0 + 1, rm, r0, rp);         // d0+1 <= 73 < 96: always in range

  int o = ((nc * DDIM + d0) * HDIM + h) * WDIM + w0;  // max ~50M, fits int

#pragma unroll 2
  for (int d = d0; d < d0 + DCHUNK; ++d) {
    // 1) ISSUE loads for plane d+2 (consumed next iteration).
    f4 nm, n0, np;
    const int zn = d + 2;
    loadPlane(zn >= DDIM ? DDIM - 1 : zn, nm, n0, np);

    // 2) Compute combos for plane d+1 from registers loaded last iteration.
    float A2[4], B2[4], C2[4];
    combos(rm, r0, rp, A2, B2, C2);
    if (d + 1 >= DDIM) {                 // only last iter of last chunk
#pragma unroll
      for (int j = 0; j < 4; ++j) { A2[j] = 0.f; B2[j] = 0.f; C2[j] = 0.f; }
    }

    // 3) Combine along d and store (nontemporal: write-once, never re-read).
    f4 gx, gy, gz;
    gx.x = A0[0] + 2.f * A1[0] + A2[0];
    gx.y = A0[1] + 2.f * A1[1] + A2[1];
    gx.z = A0[2] + 2.f * A1[2] + A2[2];
    gx.w = A0[3] + 2.f * A1[3] + A2[3];
    gy.x = B0[0] + 2.f * B1[0] + B2[0];
    gy.y = B0[1] + 2.f * B1[1] + B2[1];
    gy.z = B0[2] + 2.f * B1[2] + B2[2];
    gy.w = B0[3] + 2.f * B1[3] + B2[3];
    gz.x = C2[0] - C0[0];
    gz.y = C2[1] - C0[1];
    gz.z = C2[2] - C0[2];
    gz.w = C2[3] - C0[3];
    __builtin_nontemporal_store(gx, (f4*)(out + o));
    __builtin_nontemporal_store(gy, (f4*)(out + NTOTI + o));
    __builtin_nontemporal_store(gz, (f4*)(out + 2 * NTOTI + o));
    o += PLANE;

    // 4) Roll state (renamed away by unroll).
#pragma unroll
    for (int j = 0; j < 4; ++j) {
      A0[j] = A1[j]; B0[j] = B1[j]; C0[j] = C1[j];
      A1[j] = A2[j]; B1[j] = B2[j]; C1[j] = C2[j];
    }
    rm = nm; r0 = n0; rp = np;
  }
}

extern "C" void kernel_launch(void* const* d_in, const int* in_sizes, int n_in,
                              void* d_out, int out_size, void* d_ws, size_t ws_size,
                              hipStream_t stream) {
  const float* x = (const float*)d_in[0];
  float* out = (float*)d_out;
  dim3 block(32, 8, 1);
  dim3 grid(1, HDIM / 8, NCIMG * (DDIM / DCHUNK));  // (1, 16, 128)
  hipLaunchKernelGGL(sobel3d_fused, grid, block, 0, stream, x, out);
}